// Round 1
// baseline (484.995 us; speedup 1.0000x reference)
//
#include <hip/hip_runtime.h>

#define N_ITEMS 16384
#define D 64
#define T 8
#define H 256

// ---------------------------------------------------------------------------
// Kernel 1: per-item embedding gathers + ragged tag mean-pool.
// One wave (64 lanes) per item; lane = embedding dim.
// Writes x = [e_item | tag_mean] (N x 128) to workspace, e_dat to d_out tail.
// ---------------------------------------------------------------------------
__global__ __launch_bounds__(256) void k_gather(
    const int* __restrict__ item_ids,
    const int* __restrict__ tag_ids,
    const int* __restrict__ tag_lens,
    const float* __restrict__ item_table,
    const float* __restrict__ item_dat_table,
    const float* __restrict__ tag_table,
    float* __restrict__ x,          // [N,128]
    float* __restrict__ e_dat_out)  // [N,64]
{
    const int wave = __builtin_amdgcn_readfirstlane(threadIdx.x >> 6);
    const int lane = threadIdx.x & 63;
    const int i = blockIdx.x * 4 + wave;   // wave-uniform item index

    const int id  = item_ids[i];           // wave-uniform -> scalar load
    const int len = tag_lens[i];

    const float e_it = item_table[(size_t)id * D + lane];
    const float e_da = item_dat_table[(size_t)id * D + lane];

    float s = 0.f;
#pragma unroll
    for (int t = 0; t < T; ++t) {
        if (t < len) {                      // wave-uniform branch
            const int tg = tag_ids[i * T + t];
            s += tag_table[(size_t)tg * D + lane];
        }
    }

    x[i * 128 + lane]      = e_it;
    x[i * 128 + 64 + lane] = s / (float)len;
    e_dat_out[i * D + lane] = e_da;
}

// ---------------------------------------------------------------------------
// Kernel 2: h = relu(x @ W1[0:128,:] + b1).  x rows 128..191 are zeros in the
// reference, so W1 rows >=128 are skipped entirely.
// Block = 256 threads, thread j owns output column j for a 16-item tile.
// x addresses are block-uniform -> compiler should emit s_load_dwordx4.
// ---------------------------------------------------------------------------
__global__ __launch_bounds__(256) void k_layer1(
    const float* __restrict__ x,    // [N,128]
    const float* __restrict__ W1,   // [192,256] row-major
    const float* __restrict__ b1,   // [256]
    float* __restrict__ h)          // [N,256]
{
    const int j  = threadIdx.x;           // output column 0..255
    const int i0 = blockIdx.x * 16;       // item tile base (block-uniform)
    const float* xrow = x + (size_t)i0 * 128;

    float acc[16];
    const float bj = b1[j];
#pragma unroll
    for (int i = 0; i < 16; ++i) acc[i] = bj;

    for (int k = 0; k < 128; k += 4) {
        const float w0 = W1[(size_t)(k + 0) * H + j];
        const float w1 = W1[(size_t)(k + 1) * H + j];
        const float w2 = W1[(size_t)(k + 2) * H + j];
        const float w3 = W1[(size_t)(k + 3) * H + j];
#pragma unroll
        for (int i = 0; i < 16; ++i) {
            const float4 xv = *reinterpret_cast<const float4*>(xrow + i * 128 + k);
            acc[i] = fmaf(xv.x, w0, acc[i]);
            acc[i] = fmaf(xv.y, w1, acc[i]);
            acc[i] = fmaf(xv.z, w2, acc[i]);
            acc[i] = fmaf(xv.w, w3, acc[i]);
        }
    }

#pragma unroll
    for (int i = 0; i < 16; ++i)
        h[(size_t)(i0 + i) * H + j] = fmaxf(acc[i], 0.f);
}

// ---------------------------------------------------------------------------
// Kernel 3: out = h @ W2 + b2.  Block = 256 threads = 4 waves.
// Each wave handles 8 items; lane = output column (0..63).
// h addresses are wave-uniform (readfirstlane-forced) -> scalar loads.
// ---------------------------------------------------------------------------
__global__ __launch_bounds__(256) void k_layer2(
    const float* __restrict__ h,    // [N,256]
    const float* __restrict__ W2,   // [256,64] row-major
    const float* __restrict__ b2,   // [64]
    float* __restrict__ out)        // [N,64]
{
    const int lane = threadIdx.x & 63;
    const int wave = __builtin_amdgcn_readfirstlane(threadIdx.x >> 6);
    const int i0   = blockIdx.x * 32 + wave * 8;  // wave-uniform
    const int j    = lane;
    const float* hrow = h + (size_t)i0 * H;

    float acc[8];
    const float bj = b2[j];
#pragma unroll
    for (int i = 0; i < 8; ++i) acc[i] = bj;

    for (int k = 0; k < 256; k += 4) {
        const float w0 = W2[(size_t)(k + 0) * 64 + j];
        const float w1 = W2[(size_t)(k + 1) * 64 + j];
        const float w2v = W2[(size_t)(k + 2) * 64 + j];
        const float w3 = W2[(size_t)(k + 3) * 64 + j];
#pragma unroll
        for (int i = 0; i < 8; ++i) {
            const float4 hv = *reinterpret_cast<const float4*>(hrow + i * H + k);
            acc[i] = fmaf(hv.x, w0, acc[i]);
            acc[i] = fmaf(hv.y, w1, acc[i]);
            acc[i] = fmaf(hv.z, w2v, acc[i]);
            acc[i] = fmaf(hv.w, w3, acc[i]);
        }
    }

#pragma unroll
    for (int i = 0; i < 8; ++i)
        out[(size_t)(i0 + i) * 64 + j] = acc[i];
}

// ---------------------------------------------------------------------------
extern "C" void kernel_launch(void* const* d_in, const int* in_sizes, int n_in,
                              void* d_out, int out_size, void* d_ws, size_t ws_size,
                              hipStream_t stream) {
    const int*   item_ids       = (const int*)d_in[0];
    const int*   tag_ids        = (const int*)d_in[1];
    const int*   tag_lens       = (const int*)d_in[2];
    const float* item_table     = (const float*)d_in[3];
    const float* item_dat_table = (const float*)d_in[4];
    const float* tag_table      = (const float*)d_in[5];
    const float* W1             = (const float*)d_in[6];
    const float* b1             = (const float*)d_in[7];
    const float* W2             = (const float*)d_in[8];
    const float* b2             = (const float*)d_in[9];

    float* out       = (float*)d_out;                       // [N,64]
    float* e_dat_out = out + (size_t)N_ITEMS * D;           // [N,64] (tuple part 2)

    float* x = (float*)d_ws;                                // [N,128]  8 MB
    float* h = x + (size_t)N_ITEMS * 128;                   // [N,256] 16 MB

    k_gather<<<N_ITEMS / 4, 256, 0, stream>>>(item_ids, tag_ids, tag_lens,
                                              item_table, item_dat_table,
                                              tag_table, x, e_dat_out);
    k_layer1<<<N_ITEMS / 16, 256, 0, stream>>>(x, W1, b1, h);
    k_layer2<<<N_ITEMS / 32, 256, 0, stream>>>(h, W2, b2, out);
}

// Round 2
// 474.053 us; speedup vs baseline: 1.0231x; 1.0231x over previous
//
#include <hip/hip_runtime.h>

#define N_ITEMS 16384
#define D 64
#define T 8
#define H 256
#define TILE 16               // items per block
#define HS_STRIDE 260         // 256 + 4 pad: phase-3 item rows land on distinct banks

// ---------------------------------------------------------------------------
// Fully fused: gather + ragged tag mean-pool + 2-layer MLP tower.
// One 256-thread block handles 16 items. x and h live in LDS only (no d_ws).
//
// Phase 1  (wave = 4 items, lane = dim): embedding gathers -> xs, e_dat -> out
// Phase 2  (thread = 4 items x 4 cols): h = relu(x @ W1[0:128] + b1) -> hs
//          (x rows 128..191 of the concat are zeros -> W1 rows >=128 skipped)
// Phase 3  (thread = 1 item x 4 cols): out = h @ W2 + b2
// ---------------------------------------------------------------------------
__global__ __launch_bounds__(256) void k_fused(
    const int* __restrict__ item_ids,
    const int* __restrict__ tag_ids,
    const int* __restrict__ tag_lens,
    const float* __restrict__ item_table,
    const float* __restrict__ item_dat_table,
    const float* __restrict__ tag_table,
    const float* __restrict__ W1,   // [192,256] row-major (rows >=128 unused)
    const float* __restrict__ b1,   // [256]
    const float* __restrict__ W2,   // [256,64] row-major
    const float* __restrict__ b2,   // [64]
    float* __restrict__ out,        // [N,64]
    float* __restrict__ e_dat_out)  // [N,64]
{
    __shared__ float xs[TILE * 128];        //  8 KB
    __shared__ float hs[TILE * HS_STRIDE];  // 16.25 KB

    const int tid  = threadIdx.x;
    const int lane = tid & 63;
    const int wave = tid >> 6;
    const int i0   = blockIdx.x * TILE;

    // ---------------- Phase 1: gathers + tag mean-pool --------------------
#pragma unroll
    for (int r = 0; r < 4; ++r) {
        const int il = wave * 4 + r;          // local item (wave-uniform)
        const int gi = i0 + il;               // global item
        const int id  = item_ids[gi];         // wave-uniform -> scalar load
        const int len = tag_lens[gi];

        xs[il * 128 + lane]      = item_table[(size_t)id * D + lane];
        e_dat_out[(size_t)gi * D + lane] = item_dat_table[(size_t)id * D + lane];

        float s = 0.f;
#pragma unroll
        for (int t = 0; t < T; ++t) {
            if (t < len) {                    // wave-uniform branch
                const int tg = tag_ids[gi * T + t];
                s += tag_table[(size_t)tg * D + lane];
            }
        }
        xs[il * 128 + 64 + lane] = s / (float)len;
    }
    __syncthreads();

    // ---------------- Phase 2: h = relu(x @ W1[:128] + b1) ----------------
    {
        const int c = tid & 63;               // col group: cols 4c..4c+3
        const int g = tid >> 6;               // item group: items 4g..4g+3
        float4 acc[4];
        const float4 bj = *reinterpret_cast<const float4*>(b1 + 4 * c);
#pragma unroll
        for (int r = 0; r < 4; ++r) acc[r] = bj;

        for (int k = 0; k < 128; k += 4) {
            float4 xv[4];
#pragma unroll
            for (int r = 0; r < 4; ++r)
                xv[r] = *reinterpret_cast<const float4*>(&xs[(g * 4 + r) * 128 + k]);
            const float4 w0 = *reinterpret_cast<const float4*>(W1 + (size_t)(k + 0) * H + 4 * c);
            const float4 w1 = *reinterpret_cast<const float4*>(W1 + (size_t)(k + 1) * H + 4 * c);
            const float4 w2 = *reinterpret_cast<const float4*>(W1 + (size_t)(k + 2) * H + 4 * c);
            const float4 w3 = *reinterpret_cast<const float4*>(W1 + (size_t)(k + 3) * H + 4 * c);
#pragma unroll
            for (int r = 0; r < 4; ++r) {
                acc[r].x = fmaf(xv[r].x, w0.x, acc[r].x);
                acc[r].y = fmaf(xv[r].x, w0.y, acc[r].y);
                acc[r].z = fmaf(xv[r].x, w0.z, acc[r].z);
                acc[r].w = fmaf(xv[r].x, w0.w, acc[r].w);
                acc[r].x = fmaf(xv[r].y, w1.x, acc[r].x);
                acc[r].y = fmaf(xv[r].y, w1.y, acc[r].y);
                acc[r].z = fmaf(xv[r].y, w1.z, acc[r].z);
                acc[r].w = fmaf(xv[r].y, w1.w, acc[r].w);
                acc[r].x = fmaf(xv[r].z, w2.x, acc[r].x);
                acc[r].y = fmaf(xv[r].z, w2.y, acc[r].y);
                acc[r].z = fmaf(xv[r].z, w2.z, acc[r].z);
                acc[r].w = fmaf(xv[r].z, w2.w, acc[r].w);
                acc[r].x = fmaf(xv[r].w, w3.x, acc[r].x);
                acc[r].y = fmaf(xv[r].w, w3.y, acc[r].y);
                acc[r].z = fmaf(xv[r].w, w3.z, acc[r].z);
                acc[r].w = fmaf(xv[r].w, w3.w, acc[r].w);
            }
        }
#pragma unroll
        for (int r = 0; r < 4; ++r) {
            float4 hval;
            hval.x = fmaxf(acc[r].x, 0.f);
            hval.y = fmaxf(acc[r].y, 0.f);
            hval.z = fmaxf(acc[r].z, 0.f);
            hval.w = fmaxf(acc[r].w, 0.f);
            *reinterpret_cast<float4*>(&hs[(g * 4 + r) * HS_STRIDE + 4 * c]) = hval;
        }
    }
    __syncthreads();

    // ---------------- Phase 3: out = h @ W2 + b2 --------------------------
    {
        const int item = tid >> 4;            // 0..15
        const int cg   = tid & 15;            // cols 4cg..4cg+3
        float4 acc = *reinterpret_cast<const float4*>(b2 + 4 * cg);
        const float* hrow = &hs[item * HS_STRIDE];

        for (int k = 0; k < 256; k += 4) {
            const float4 hv = *reinterpret_cast<const float4*>(&hrow[k]);
            const float4 w0 = *reinterpret_cast<const float4*>(W2 + (size_t)(k + 0) * 64 + 4 * cg);
            const float4 w1 = *reinterpret_cast<const float4*>(W2 + (size_t)(k + 1) * 64 + 4 * cg);
            const float4 w2 = *reinterpret_cast<const float4*>(W2 + (size_t)(k + 2) * 64 + 4 * cg);
            const float4 w3 = *reinterpret_cast<const float4*>(W2 + (size_t)(k + 3) * 64 + 4 * cg);
            acc.x = fmaf(hv.x, w0.x, acc.x);
            acc.y = fmaf(hv.x, w0.y, acc.y);
            acc.z = fmaf(hv.x, w0.z, acc.z);
            acc.w = fmaf(hv.x, w0.w, acc.w);
            acc.x = fmaf(hv.y, w1.x, acc.x);
            acc.y = fmaf(hv.y, w1.y, acc.y);
            acc.z = fmaf(hv.y, w1.z, acc.z);
            acc.w = fmaf(hv.y, w1.w, acc.w);
            acc.x = fmaf(hv.z, w2.x, acc.x);
            acc.y = fmaf(hv.z, w2.y, acc.y);
            acc.z = fmaf(hv.z, w2.z, acc.z);
            acc.w = fmaf(hv.z, w2.w, acc.w);
            acc.x = fmaf(hv.w, w3.x, acc.x);
            acc.y = fmaf(hv.w, w3.y, acc.y);
            acc.z = fmaf(hv.w, w3.z, acc.z);
            acc.w = fmaf(hv.w, w3.w, acc.w);
        }
        *reinterpret_cast<float4*>(out + (size_t)(i0 + item) * 64 + 4 * cg) = acc;
    }
}

// ---------------------------------------------------------------------------
extern "C" void kernel_launch(void* const* d_in, const int* in_sizes, int n_in,
                              void* d_out, int out_size, void* d_ws, size_t ws_size,
                              hipStream_t stream) {
    const int*   item_ids       = (const int*)d_in[0];
    const int*   tag_ids        = (const int*)d_in[1];
    const int*   tag_lens       = (const int*)d_in[2];
    const float* item_table     = (const float*)d_in[3];
    const float* item_dat_table = (const float*)d_in[4];
    const float* tag_table      = (const float*)d_in[5];
    const float* W1             = (const float*)d_in[6];
    const float* b1             = (const float*)d_in[7];
    const float* W2             = (const float*)d_in[8];
    const float* b2             = (const float*)d_in[9];

    float* out       = (float*)d_out;               // [N,64]
    float* e_dat_out = out + (size_t)N_ITEMS * D;   // [N,64] (tuple part 2)

    k_fused<<<N_ITEMS / TILE, 256, 0, stream>>>(item_ids, tag_ids, tag_lens,
                                                item_table, item_dat_table, tag_table,
                                                W1, b1, W2, b2, out, e_dat_out);
}